// Round 1
// baseline (6512.192 us; speedup 1.0000x reference)
//
#include <hip/hip_runtime.h>
#include <cstdint>
#include <cstddef>

#define M_ROWS 32768   // B*N
#define CDIM   512
#define KRANK  150

// ================= GEMM: out[m][n] = sum_k X[m][k]*W[n][k] + bias[n] ================
// RESIDUAL epilogue: out = gamma*(acc+bias) + xres
template<bool RESIDUAL>
__global__ __launch_bounds__(256)
void gemm_nt(const float* __restrict__ X, const float* __restrict__ W,
             const float* __restrict__ bias, float* __restrict__ out,
             int N, int ostride,
             const float* __restrict__ xres, const float* __restrict__ gammap)
{
  __shared__ __align__(16) float as[16][132];
  __shared__ __align__(16) float bs[16][132];
  const int m0 = blockIdx.y * 128;
  const int n0 = blockIdx.x * 128;
  const int tid = threadIdx.x;
  const int tx = tid & 15, ty = tid >> 4;

  float acc[8][8];
#pragma unroll
  for (int i = 0; i < 8; ++i)
#pragma unroll
    for (int j = 0; j < 8; ++j) acc[i][j] = 0.f;

  for (int kt = 0; kt < 512; kt += 16) {
#pragma unroll
    for (int h = 0; h < 2; ++h) {
      const int f4 = tid + h * 256;      // 0..511
      const int row = f4 >> 2;           // 0..127
      const int kc = (f4 & 3) * 4;       // 0,4,8,12
      const float4 v = *(const float4*)&X[(size_t)(m0 + row) * 512 + kt + kc];
      as[kc + 0][row] = v.x; as[kc + 1][row] = v.y;
      as[kc + 2][row] = v.z; as[kc + 3][row] = v.w;
      const int wrow = n0 + row;
      float4 wv = make_float4(0.f, 0.f, 0.f, 0.f);
      if (wrow < N) wv = *(const float4*)&W[(size_t)wrow * 512 + kt + kc];
      bs[kc + 0][row] = wv.x; bs[kc + 1][row] = wv.y;
      bs[kc + 2][row] = wv.z; bs[kc + 3][row] = wv.w;
    }
    __syncthreads();
#pragma unroll 4
    for (int k = 0; k < 16; ++k) {
      float a[8], b[8];
      *(float4*)&a[0] = *(const float4*)&as[k][ty * 8];
      *(float4*)&a[4] = *(const float4*)&as[k][ty * 8 + 4];
      *(float4*)&b[0] = *(const float4*)&bs[k][tx * 8];
      *(float4*)&b[4] = *(const float4*)&bs[k][tx * 8 + 4];
#pragma unroll
      for (int i = 0; i < 8; ++i)
#pragma unroll
        for (int j = 0; j < 8; ++j)
          acc[i][j] = fmaf(a[i], b[j], acc[i][j]);
    }
    __syncthreads();
  }

  // epilogue
  float bvv[8];
#pragma unroll
  for (int j = 0; j < 8; ++j) {
    const int n = n0 + tx * 8 + j;
    bvv[j] = (n < N) ? bias[n] : 0.f;
  }
  const float g = RESIDUAL ? gammap[0] : 0.f;
  const int nb = n0 + tx * 8;
#pragma unroll
  for (int i = 0; i < 8; ++i) {
    const int m = m0 + ty * 8 + i;
    float vals[8];
#pragma unroll
    for (int j = 0; j < 8; ++j) vals[j] = acc[i][j] + bvv[j];
    if (RESIDUAL) {
      const float4 xr0 = *(const float4*)&xres[(size_t)m * CDIM + nb];
      const float4 xr1 = *(const float4*)&xres[(size_t)m * CDIM + nb + 4];
      vals[0] = fmaf(g, vals[0], xr0.x); vals[1] = fmaf(g, vals[1], xr0.y);
      vals[2] = fmaf(g, vals[2], xr0.z); vals[3] = fmaf(g, vals[3], xr0.w);
      vals[4] = fmaf(g, vals[4], xr1.x); vals[5] = fmaf(g, vals[5], xr1.y);
      vals[6] = fmaf(g, vals[6], xr1.z); vals[7] = fmaf(g, vals[7], xr1.w);
    }
    if (((ostride & 3) == 0) && (nb + 8 <= N)) {
      *(float4*)&out[(size_t)m * ostride + nb] =
          make_float4(vals[0], vals[1], vals[2], vals[3]);
      *(float4*)&out[(size_t)m * ostride + nb + 4] =
          make_float4(vals[4], vals[5], vals[6], vals[7]);
    } else {
#pragma unroll
      for (int j = 0; j < 8; ++j)
        if (nb + j < N) out[(size_t)m * ostride + nb + j] = vals[j];
    }
  }
}

// ================= Flash attention (fp32 VALU, bf16 V in LDS) =================
// grid: 1024 blocks (8 batches x 128 row-tiles of 32 rows); 256 threads = 4 waves.
// Wave w owns local rows w*8..w*8+7. S phase: lanes 0-31 = keys for even row,
// lanes 32-63 = same keys for odd row. PV phase: lane owns cols lane*8..lane*8+7.
__global__ __launch_bounds__(256)
void attn_kernel(const float* __restrict__ Q, const float* __restrict__ Kf,
                 const float* __restrict__ V, float* __restrict__ O)
{
  __shared__ __align__(16) float qs[32][152];          // 19456 B (pad cols zeroed)
  __shared__ __align__(16) float ks[32][156];          // 19968 B
  __shared__ __align__(16) unsigned short vs[32][512]; // 32768 B (bf16)

  const int bidx = blockIdx.x;
  const int b = bidx >> 7;
  const int tile = bidx & 127;
  const int r0 = (b << 12) + tile * 32;  // global q-row base
  const int kbase = (b << 12);
  const int tid = threadIdx.x;
  const int w = tid >> 6;
  const int lane = tid & 63;

  for (int i = tid; i < 32 * 152; i += 256) {
    const int row = i / 152, col = i - row * 152;
    qs[row][col] = (col < KRANK) ? Q[(size_t)(r0 + row) * KRANK + col] : 0.f;
  }

  float m_s[8], l_s[8], acc[8][8];
#pragma unroll
  for (int r = 0; r < 8; ++r) {
    m_s[r] = -3.0e38f; l_s[r] = 0.f;
#pragma unroll
    for (int c = 0; c < 8; ++c) acc[r][c] = 0.f;
  }

  const float4* V4 = (const float4*)V;

  for (int kt = 0; kt < 128; ++kt) {
    __syncthreads();  // previous tile fully consumed (also covers qs staging)
    const int kb = kbase + kt * 32;
    for (int i = tid; i < 32 * 156; i += 256) {
      const int row = i / 156, col = i - row * 156;
      ks[row][col] = (col < KRANK) ? Kf[(size_t)(kb + row) * KRANK + col] : 0.f;
    }
    for (int i4 = tid; i4 < 32 * 128; i4 += 256) {
      const int row = i4 >> 7, c4 = i4 & 127;
      const float4 f = V4[(size_t)(kb + row) * 128 + c4];
      uint32_t ux = __float_as_uint(f.x); ux += 0x7fffu + ((ux >> 16) & 1u);
      uint32_t uy = __float_as_uint(f.y); uy += 0x7fffu + ((uy >> 16) & 1u);
      uint32_t uz = __float_as_uint(f.z); uz += 0x7fffu + ((uz >> 16) & 1u);
      uint32_t uw = __float_as_uint(f.w); uw += 0x7fffu + ((uw >> 16) & 1u);
      uint2 packed;
      packed.x = (ux >> 16) | (uy & 0xffff0000u);
      packed.y = (uz >> 16) | (uw & 0xffff0000u);
      *(uint2*)&vs[row][c4 * 4] = packed;
    }
    __syncthreads();

#pragma unroll
    for (int p = 0; p < 4; ++p) {
      const int re = 2 * p, ro = 2 * p + 1;
      const int lr = w * 8 + re + (lane >> 5);
      const int kk = lane & 31;
      const float4* q4 = (const float4*)&qs[lr][0];
      const float4* k4 = (const float4*)&ks[kk][0];
      float sp[8];
#pragma unroll
      for (int t = 0; t < 8; ++t) sp[t] = 0.f;
#pragma unroll 4
      for (int j = 0; j < 19; ++j) {   // 19*8 = 152 cols (pad cols are zero)
        const float4 a0 = q4[2 * j], a1 = q4[2 * j + 1];
        const float4 c0 = k4[2 * j], c1 = k4[2 * j + 1];
        sp[0] = fmaf(a0.x, c0.x, sp[0]);
        sp[1] = fmaf(a0.y, c0.y, sp[1]);
        sp[2] = fmaf(a0.z, c0.z, sp[2]);
        sp[3] = fmaf(a0.w, c0.w, sp[3]);
        sp[4] = fmaf(a1.x, c1.x, sp[4]);
        sp[5] = fmaf(a1.y, c1.y, sp[5]);
        sp[6] = fmaf(a1.z, c1.z, sp[6]);
        sp[7] = fmaf(a1.w, c1.w, sp[7]);
      }
      const float s = ((sp[0] + sp[1]) + (sp[2] + sp[3])) +
                      ((sp[4] + sp[5]) + (sp[6] + sp[7]));

      float tm = s;
      tm = fmaxf(tm, __shfl_xor(tm, 1));
      tm = fmaxf(tm, __shfl_xor(tm, 2));
      tm = fmaxf(tm, __shfl_xor(tm, 4));
      tm = fmaxf(tm, __shfl_xor(tm, 8));
      tm = fmaxf(tm, __shfl_xor(tm, 16));
      const float tmx = __shfl_xor(tm, 32);
      const float tme = (lane < 32) ? tm : tmx;
      const float tmo = (lane < 32) ? tmx : tm;

      const float me_new = fmaxf(m_s[re], tme);
      const float mo_new = fmaxf(m_s[ro], tmo);
      const float alpha_e = __expf(m_s[re] - me_new);
      const float alpha_o = __expf(m_s[ro] - mo_new);
      m_s[re] = me_new; m_s[ro] = mo_new;

      const float pval = __expf(s - ((lane < 32) ? me_new : mo_new));
      float rsum = pval;
      rsum += __shfl_xor(rsum, 1);
      rsum += __shfl_xor(rsum, 2);
      rsum += __shfl_xor(rsum, 4);
      rsum += __shfl_xor(rsum, 8);
      rsum += __shfl_xor(rsum, 16);
      const float rsx = __shfl_xor(rsum, 32);
      const float sume = (lane < 32) ? rsum : rsx;
      const float sumo = (lane < 32) ? rsx : rsum;
      l_s[re] = l_s[re] * alpha_e + sume;
      l_s[ro] = l_s[ro] * alpha_o + sumo;
#pragma unroll
      for (int c = 0; c < 8; ++c) { acc[re][c] *= alpha_e; acc[ro][c] *= alpha_o; }

#pragma unroll 4
      for (int k2 = 0; k2 < 32; ++k2) {
        const float pe = __shfl(pval, k2);
        const float po = __shfl(pval, k2 + 32);
        const uint4 vv = *(const uint4*)&vs[k2][lane * 8];
        const float f0 = __uint_as_float(vv.x << 16);
        const float f1 = __uint_as_float(vv.x & 0xffff0000u);
        const float f2 = __uint_as_float(vv.y << 16);
        const float f3 = __uint_as_float(vv.y & 0xffff0000u);
        const float f4v = __uint_as_float(vv.z << 16);
        const float f5 = __uint_as_float(vv.z & 0xffff0000u);
        const float f6 = __uint_as_float(vv.w << 16);
        const float f7 = __uint_as_float(vv.w & 0xffff0000u);
        acc[re][0] = fmaf(pe, f0, acc[re][0]);
        acc[re][1] = fmaf(pe, f1, acc[re][1]);
        acc[re][2] = fmaf(pe, f2, acc[re][2]);
        acc[re][3] = fmaf(pe, f3, acc[re][3]);
        acc[re][4] = fmaf(pe, f4v, acc[re][4]);
        acc[re][5] = fmaf(pe, f5, acc[re][5]);
        acc[re][6] = fmaf(pe, f6, acc[re][6]);
        acc[re][7] = fmaf(pe, f7, acc[re][7]);
        acc[ro][0] = fmaf(po, f0, acc[ro][0]);
        acc[ro][1] = fmaf(po, f1, acc[ro][1]);
        acc[ro][2] = fmaf(po, f2, acc[ro][2]);
        acc[ro][3] = fmaf(po, f3, acc[ro][3]);
        acc[ro][4] = fmaf(po, f4v, acc[ro][4]);
        acc[ro][5] = fmaf(po, f5, acc[ro][5]);
        acc[ro][6] = fmaf(po, f6, acc[ro][6]);
        acc[ro][7] = fmaf(po, f7, acc[ro][7]);
      }
    }
  }

  // epilogue: feats = acc / l
#pragma unroll
  for (int r = 0; r < 8; ++r) {
    const float inv = 1.f / l_s[r];
    const int grow = r0 + w * 8 + r;
    float* op = O + (size_t)grow * CDIM + lane * 8;
    *(float4*)op = make_float4(acc[r][0] * inv, acc[r][1] * inv,
                               acc[r][2] * inv, acc[r][3] * inv);
    *(float4*)(op + 4) = make_float4(acc[r][4] * inv, acc[r][5] * inv,
                                     acc[r][6] * inv, acc[r][7] * inv);
  }
}

extern "C" void kernel_launch(void* const* d_in, const int* in_sizes, int n_in,
                              void* d_out, int out_size, void* d_ws, size_t ws_size,
                              hipStream_t stream)
{
  const float* x     = (const float*)d_in[0];
  const float* Wq    = (const float*)d_in[1];
  const float* bq    = (const float*)d_in[2];
  const float* Wk    = (const float*)d_in[3];
  const float* bk    = (const float*)d_in[4];
  const float* Wv    = (const float*)d_in[5];
  const float* bv    = (const float*)d_in[6];
  const float* Wres  = (const float*)d_in[7];
  const float* bres  = (const float*)d_in[8];
  const float* gamma = (const float*)d_in[9];

  float* seg_map  = (float*)d_out;                         // 32768 x 150
  float* feat_map = seg_map + (size_t)M_ROWS * KRANK;      // 32768 x 512

  // workspace: segft (19.7MB) + v (67.1MB) + feats (67.1MB) = 153.9 MB
  float* segft = (float*)d_ws;
  float* vbuf  = segft + (size_t)M_ROWS * KRANK;
  float* feats = vbuf + (size_t)M_ROWS * CDIM;

  dim3 blk(256);
  gemm_nt<false><<<dim3(2, 256), blk, 0, stream>>>(x, Wq, bq, seg_map, KRANK, KRANK, nullptr, nullptr);
  gemm_nt<false><<<dim3(2, 256), blk, 0, stream>>>(x, Wk, bk, segft,   KRANK, KRANK, nullptr, nullptr);
  gemm_nt<false><<<dim3(4, 256), blk, 0, stream>>>(x, Wv, bv, vbuf,    CDIM,  CDIM,  nullptr, nullptr);
  attn_kernel<<<dim3(1024), blk, 0, stream>>>(seg_map, segft, vbuf, feats);
  gemm_nt<true><<<dim3(4, 256), blk, 0, stream>>>(feats, Wres, bres, feat_map, CDIM, CDIM, x, gamma);
}

// Round 2
// 2313.794 us; speedup vs baseline: 2.8145x; 2.8145x over previous
//
#include <hip/hip_runtime.h>
#include <cstdint>
#include <cstddef>

#define M_ROWS 32768   // B*N
#define CDIM   512
#define KRANK  150
#define KPAD   160     // padded rank for MFMA (zeros beyond 150)

typedef __bf16 bf16x8 __attribute__((ext_vector_type(8)));
typedef float  f32x4  __attribute__((ext_vector_type(4)));

union U16B { uint4 u; bf16x8 b; };
static __device__ __forceinline__ bf16x8 u2b(uint4 u) { U16B x; x.u = u; return x.b; }

static __device__ __forceinline__ unsigned short f2bf(float f) {
  uint32_t u = __float_as_uint(f);
  u += 0x7fffu + ((u >> 16) & 1u);
  return (unsigned short)(u >> 16);
}

// ================= GEMM: out[m][n] = sum_k X[m][k]*W[n][k] + bias[n] ================
// MODE 0: plain fp32 out
// MODE 1: residual: out = gamma*(acc+bias) + xres
// MODE 2: Q: fp32 out (stride ostride) + aux = packed hi/lo bf16 [m][320] (cols>=150 zero)
// MODE 3: K: aux packed hi/lo bf16 only
// MODE 4: V: aux = V^T bf16 [b][col][4096]
template<int MODE>
__global__ __launch_bounds__(256)
void gemm_nt(const float* __restrict__ X, const float* __restrict__ W,
             const float* __restrict__ bias, float* __restrict__ out,
             int N, int ostride,
             const float* __restrict__ xres, const float* __restrict__ gammap,
             unsigned short* __restrict__ aux)
{
  __shared__ __align__(16) float as[16][132];
  __shared__ __align__(16) float bs[16][132];
  const int m0 = blockIdx.y * 128;
  const int n0 = blockIdx.x * 128;
  const int tid = threadIdx.x;
  const int tx = tid & 15, ty = tid >> 4;

  float acc[8][8];
#pragma unroll
  for (int i = 0; i < 8; ++i)
#pragma unroll
    for (int j = 0; j < 8; ++j) acc[i][j] = 0.f;

  for (int kt = 0; kt < 512; kt += 16) {
#pragma unroll
    for (int h = 0; h < 2; ++h) {
      const int f4 = tid + h * 256;      // 0..511
      const int row = f4 >> 2;           // 0..127
      const int kc = (f4 & 3) * 4;       // 0,4,8,12
      const float4 v = *(const float4*)&X[(size_t)(m0 + row) * 512 + kt + kc];
      as[kc + 0][row] = v.x; as[kc + 1][row] = v.y;
      as[kc + 2][row] = v.z; as[kc + 3][row] = v.w;
      const int wrow = n0 + row;
      float4 wv = make_float4(0.f, 0.f, 0.f, 0.f);
      if (wrow < N) wv = *(const float4*)&W[(size_t)wrow * 512 + kt + kc];
      bs[kc + 0][row] = wv.x; bs[kc + 1][row] = wv.y;
      bs[kc + 2][row] = wv.z; bs[kc + 3][row] = wv.w;
    }
    __syncthreads();
#pragma unroll 4
    for (int k = 0; k < 16; ++k) {
      float a[8], b[8];
      *(float4*)&a[0] = *(const float4*)&as[k][ty * 8];
      *(float4*)&a[4] = *(const float4*)&as[k][ty * 8 + 4];
      *(float4*)&b[0] = *(const float4*)&bs[k][tx * 8];
      *(float4*)&b[4] = *(const float4*)&bs[k][tx * 8 + 4];
#pragma unroll
      for (int i = 0; i < 8; ++i)
#pragma unroll
        for (int j = 0; j < 8; ++j)
          acc[i][j] = fmaf(a[i], b[j], acc[i][j]);
    }
    __syncthreads();
  }

  // epilogue
  float bvv[8];
#pragma unroll
  for (int j = 0; j < 8; ++j) {
    const int n = n0 + tx * 8 + j;
    bvv[j] = (n < N) ? bias[n] : 0.f;
  }
  const int nb = n0 + tx * 8;

  if (MODE == 4) {
    // transposed bf16 store: VT[b][col][key]
    const int b = m0 >> 12;
    const int key0 = (m0 & 4095) + ty * 8;
#pragma unroll
    for (int j = 0; j < 8; ++j) {
      const int col = nb + j;
      unsigned short o8[8];
#pragma unroll
      for (int i = 0; i < 8; ++i) o8[i] = f2bf(acc[i][j] + bvv[j]);
      *(uint4*)&aux[((size_t)(b * 512 + col)) * 4096 + key0] = *(uint4*)&o8[0];
    }
    return;
  }

  const float g = (MODE == 1) ? gammap[0] : 0.f;
#pragma unroll
  for (int i = 0; i < 8; ++i) {
    const int m = m0 + ty * 8 + i;
    float vals[8];
#pragma unroll
    for (int j = 0; j < 8; ++j) vals[j] = acc[i][j] + bvv[j];

    if (MODE == 1) {
      const float4 xr0 = *(const float4*)&xres[(size_t)m * CDIM + nb];
      const float4 xr1 = *(const float4*)&xres[(size_t)m * CDIM + nb + 4];
      vals[0] = fmaf(g, vals[0], xr0.x); vals[1] = fmaf(g, vals[1], xr0.y);
      vals[2] = fmaf(g, vals[2], xr0.z); vals[3] = fmaf(g, vals[3], xr0.w);
      vals[4] = fmaf(g, vals[4], xr1.x); vals[5] = fmaf(g, vals[5], xr1.y);
      vals[6] = fmaf(g, vals[6], xr1.z); vals[7] = fmaf(g, vals[7], xr1.w);
      *(float4*)&out[(size_t)m * ostride + nb] = make_float4(vals[0], vals[1], vals[2], vals[3]);
      *(float4*)&out[(size_t)m * ostride + nb + 4] = make_float4(vals[4], vals[5], vals[6], vals[7]);
    } else if (MODE == 0) {
#pragma unroll
      for (int j = 0; j < 8; ++j)
        if (nb + j < N) out[(size_t)m * ostride + nb + j] = vals[j];
    } else {  // MODE 2 / 3: hi/lo bf16 pack (cols >= 150 zeroed), optional fp32 out
      unsigned short hi8[8], lo8[8];
#pragma unroll
      for (int j = 0; j < 8; ++j) {
        const int n = nb + j;
        float v = (n < KRANK) ? vals[j] : 0.f;
        if (MODE == 2 && n < KRANK) out[(size_t)m * ostride + n] = v;
        const unsigned short h = f2bf(v);
        hi8[j] = h;
        const float hf = __uint_as_float(((uint32_t)h) << 16);
        lo8[j] = f2bf(v - hf);
      }
      if (nb < KPAD) {
        *(uint4*)&aux[(size_t)m * 320 + nb]       = *(uint4*)&hi8[0];
        *(uint4*)&aux[(size_t)m * 320 + 160 + nb] = *(uint4*)&lo8[0];
      }
    }
  }
}

// ================= MFMA flash attention =================
// 256 thr / 4 waves. Q-tile 64 rows (wave w owns rowtile w => wave-local softmax),
// key-tile 32, column-split x2 (block handles 256 of 512 V-cols).
// S = Qhi*Khi + Qhi*Klo + Qlo*Khi (split bf16 ~ fp32 logits). PV in bf16 MFMA.
__global__ __launch_bounds__(256, 2)
void attn_mfma(const unsigned short* __restrict__ Qc,   // [32768][320] hi|lo
               const unsigned short* __restrict__ Kc,   // [32768][320] hi|lo
               const unsigned short* __restrict__ VT,   // [8][512][4096] bf16
               float* __restrict__ O)                   // [32768][512] fp32
{
  __shared__ __align__(16) unsigned short klds[32 * 328];  // 32 keys x (320 +8 pad)
  __shared__ __align__(16) unsigned short vtl[256 * 40];   // 256 cols x (32 keys +8 pad)
  __shared__ __align__(16) unsigned short plds[64 * 40];   // 64 qrows x (32 keys +8 pad)
  __shared__ __align__(16) float alpha_l[64];
  __shared__ __align__(16) float l_l[64];
  __shared__ int flags[4];

  const int bid = blockIdx.x;
  const int b   = bid >> 7;
  const int rem = bid & 127;
  const int qt  = rem >> 1;
  const int ch  = rem & 1;          // column half
  const int r0  = (b << 12) + qt * 64;
  const int cb0 = ch * 256;

  const int tid  = threadIdx.x;
  const int w    = tid >> 6;        // wave = rowtile
  const int lane = tid & 63;
  const int quad = lane >> 4;
  const int cq   = lane & 15;

  // ---- persistent Q fragments (A-operand layout) ----
  bf16x8 qhi[5], qlo[5];
  {
    const size_t qrow = (size_t)(r0 + w * 16 + cq) * 320;
#pragma unroll
    for (int c = 0; c < 5; ++c) {
      qhi[c] = u2b(*(const uint4*)(Qc + qrow + c * 32 + quad * 8));
      qlo[c] = u2b(*(const uint4*)(Qc + qrow + 160 + c * 32 + quad * 8));
    }
  }

  // ---- state ----
  f32x4 acc4[4][4];
#pragma unroll
  for (int rt = 0; rt < 4; ++rt)
#pragma unroll
    for (int i = 0; i < 4; ++i) acc4[rt][i] = (f32x4){0.f, 0.f, 0.f, 0.f};
  float mreg[4], lreg[4];
#pragma unroll
  for (int r = 0; r < 4; ++r) { mreg[r] = -3.0e38f; lreg[r] = 0.f; }

  // ---- prefetch tile 0 ----
  uint4 pk[5], pv[4];
  {
    const unsigned short* kb_p = Kc + (size_t)(b * 4096) * 320;
#pragma unroll
    for (int j = 0; j < 5; ++j) pk[j] = *(const uint4*)(kb_p + (tid + 256 * j) * 8);
    const unsigned short* vb_p = VT + ((size_t)(b * 512 + cb0 + tid)) * 4096;
#pragma unroll
    for (int j = 0; j < 4; ++j) pv[j] = *(const uint4*)(vb_p + j * 8);
  }

  for (int kt = 0; kt < 128; ++kt) {
    __syncthreads();  // A: previous iteration's LDS readers done

    // stage K (hi|lo packed rows) and V^T tile
#pragma unroll
    for (int j = 0; j < 5; ++j) {
      const int f = (tid + 256 * j) * 8;   // flat ushort idx in 32x320 tile
      const int row = f / 320, off = f - row * 320;
      *(uint4*)&klds[row * 328 + off] = pk[j];
    }
#pragma unroll
    for (int j = 0; j < 4; ++j) *(uint4*)&vtl[tid * 40 + j * 8] = pv[j];

    // issue prefetch for next tile (clamped; redundant last-iter load is harmless)
    {
      const int ktn = (kt < 127) ? kt + 1 : 127;
      const unsigned short* kb_p = Kc + (size_t)(b * 4096 + ktn * 32) * 320;
#pragma unroll
      for (int j = 0; j < 5; ++j) pk[j] = *(const uint4*)(kb_p + (tid + 256 * j) * 8);
      const unsigned short* vb_p = VT + ((size_t)(b * 512 + cb0 + tid)) * 4096 + ktn * 32;
#pragma unroll
      for (int j = 0; j < 4; ++j) pv[j] = *(const uint4*)(vb_p + j * 8);
    }

    __syncthreads();  // B: staging visible

    // ---- S phase: wave w computes rows [w*16, w*16+16) x 32 keys ----
    f32x4 S0 = (f32x4){0.f, 0.f, 0.f, 0.f};
    f32x4 S1 = (f32x4){0.f, 0.f, 0.f, 0.f};
#pragma unroll
    for (int c = 0; c < 5; ++c) {
      const int ko = c * 32 + quad * 8;
      const bf16x8 kh0 = u2b(*(const uint4*)&klds[cq * 328 + ko]);
      const bf16x8 kl0 = u2b(*(const uint4*)&klds[cq * 328 + 160 + ko]);
      const bf16x8 kh1 = u2b(*(const uint4*)&klds[(16 + cq) * 328 + ko]);
      const bf16x8 kl1 = u2b(*(const uint4*)&klds[(16 + cq) * 328 + 160 + ko]);
      S0 = __builtin_amdgcn_mfma_f32_16x16x32_bf16(qhi[c], kh0, S0, 0, 0, 0);
      S1 = __builtin_amdgcn_mfma_f32_16x16x32_bf16(qhi[c], kh1, S1, 0, 0, 0);
      S0 = __builtin_amdgcn_mfma_f32_16x16x32_bf16(qhi[c], kl0, S0, 0, 0, 0);
      S1 = __builtin_amdgcn_mfma_f32_16x16x32_bf16(qhi[c], kl1, S1, 0, 0, 0);
      S0 = __builtin_amdgcn_mfma_f32_16x16x32_bf16(qlo[c], kh0, S0, 0, 0, 0);
      S1 = __builtin_amdgcn_mfma_f32_16x16x32_bf16(qlo[c], kh1, S1, 0, 0, 0);
    }

    // ---- online softmax (rows = quad*4+r, keys = sub*16 + cq) ----
    float alph[4];
    bool upd = false;
#pragma unroll
    for (int r = 0; r < 4; ++r) {
      const float s0 = S0[r], s1 = S1[r];
      float t = fmaxf(s0, s1);
      t = fmaxf(t, __shfl_xor(t, 1));
      t = fmaxf(t, __shfl_xor(t, 2));
      t = fmaxf(t, __shfl_xor(t, 4));
      t = fmaxf(t, __shfl_xor(t, 8));
      const float mo = mreg[r];
      const float mn = fmaxf(mo, t);
      upd = upd || (mn > mo);
      const float al = __expf(mo - mn);
      const float p0 = __expf(s0 - mn);
      const float p1 = __expf(s1 - mn);
      float ts = p0 + p1;
      ts += __shfl_xor(ts, 1);
      ts += __shfl_xor(ts, 2);
      ts += __shfl_xor(ts, 4);
      ts += __shfl_xor(ts, 8);
      lreg[r] = lreg[r] * al + ts;
      mreg[r] = mn;
      alph[r] = al;
      const int prow = (w * 16 + quad * 4 + r) * 40;
      plds[prow + cq]      = f2bf(p0);
      plds[prow + 16 + cq] = f2bf(p1);
    }
    const int anyu = __any(upd);
    if (lane == 0) flags[w] = anyu;
    if (cq == 0) {
#pragma unroll
      for (int r = 0; r < 4; ++r) alpha_l[w * 16 + quad * 4 + r] = alph[r];
    }

    __syncthreads();  // C: P / alpha / flags visible

    // ---- PV phase: all waves, wave w owns cols [w*64, w*64+64) of this half ----
    bf16x8 vb[4];
#pragma unroll
    for (int i = 0; i < 4; ++i)
      vb[i] = u2b(*(const uint4*)&vtl[((w * 4 + i) * 16 + cq) * 40 + quad * 8]);
#pragma unroll
    for (int rt = 0; rt < 4; ++rt) {
      if (flags[rt]) {
        const f32x4 av = *(const f32x4*)&alpha_l[rt * 16 + quad * 4];
#pragma unroll
        for (int i = 0; i < 4; ++i) {
          acc4[rt][i][0] *= av[0]; acc4[rt][i][1] *= av[1];
          acc4[rt][i][2] *= av[2]; acc4[rt][i][3] *= av[3];
        }
      }
      const bf16x8 pa = u2b(*(const uint4*)&plds[(rt * 16 + cq) * 40 + quad * 8]);
#pragma unroll
      for (int i = 0; i < 4; ++i)
        acc4[rt][i] = __builtin_amdgcn_mfma_f32_16x16x32_bf16(pa, vb[i], acc4[rt][i], 0, 0, 0);
    }
  }

  // ---- epilogue: O = acc / l ----
  if (cq == 0) {
#pragma unroll
    for (int r = 0; r < 4; ++r) l_l[w * 16 + quad * 4 + r] = lreg[r];
  }
  __syncthreads();
#pragma unroll
  for (int rt = 0; rt < 4; ++rt) {
    const f32x4 lv = *(const f32x4*)&l_l[rt * 16 + quad * 4];
    const f32x4 inv = (f32x4){1.f / lv[0], 1.f / lv[1], 1.f / lv[2], 1.f / lv[3]};
#pragma unroll
    for (int i = 0; i < 4; ++i) {
      const int col = cb0 + (w * 4 + i) * 16 + cq;
#pragma unroll
      for (int r = 0; r < 4; ++r) {
        const int grow = r0 + rt * 16 + quad * 4 + r;
        O[(size_t)grow * CDIM + col] = acc4[rt][i][r] * inv[r];
      }
    }
  }
}

extern "C" void kernel_launch(void* const* d_in, const int* in_sizes, int n_in,
                              void* d_out, int out_size, void* d_ws, size_t ws_size,
                              hipStream_t stream)
{
  const float* x     = (const float*)d_in[0];
  const float* Wq    = (const float*)d_in[1];
  const float* bq    = (const float*)d_in[2];
  const float* Wk    = (const float*)d_in[3];
  const float* bk    = (const float*)d_in[4];
  const float* Wv    = (const float*)d_in[5];
  const float* bv    = (const float*)d_in[6];
  const float* Wres  = (const float*)d_in[7];
  const float* bres  = (const float*)d_in[8];
  const float* gamma = (const float*)d_in[9];

  float* seg_map  = (float*)d_out;                         // 32768 x 150
  float* feat_map = seg_map + (size_t)M_ROWS * KRANK;      // 32768 x 512

  // workspace layout (bytes): Qcomb 21.0MB | Kcomb 21.0MB | VT 33.5MB | feats 67.1MB
  unsigned short* Qcomb = (unsigned short*)d_ws;                       // [32768][320]
  unsigned short* Kcomb = Qcomb + (size_t)M_ROWS * 320;                // [32768][320]
  unsigned short* VTb   = Kcomb + (size_t)M_ROWS * 320;                // [8][512][4096]
  float*          feats = (float*)(VTb + (size_t)M_ROWS * CDIM);       // [32768][512]

  dim3 blk(256);
  gemm_nt<2><<<dim3(2, 256), blk, 0, stream>>>(x, Wq, bq, seg_map, KRANK, KRANK, nullptr, nullptr, Qcomb);
  gemm_nt<3><<<dim3(2, 256), blk, 0, stream>>>(x, Wk, bk, nullptr,  KRANK, KRANK, nullptr, nullptr, Kcomb);
  gemm_nt<4><<<dim3(4, 256), blk, 0, stream>>>(x, Wv, bv, nullptr,  CDIM,  CDIM,  nullptr, nullptr, VTb);
  attn_mfma<<<dim3(1024), blk, 0, stream>>>(Qcomb, Kcomb, VTb, feats);
  gemm_nt<1><<<dim3(4, 256), blk, 0, stream>>>(feats, Wres, bres, feat_map, CDIM, CDIM, x, gamma, nullptr);
}

// Round 5
// 1894.361 us; speedup vs baseline: 3.4377x; 1.2214x over previous
//
#include <hip/hip_runtime.h>
#include <cstdint>
#include <cstddef>

#define M_ROWS 32768   // B*N
#define CDIM   512
#define KRANK  150
#define KPAD   160     // padded rank for MFMA (zeros beyond 150)

typedef __bf16 bf16x8 __attribute__((ext_vector_type(8)));
typedef float  f32x4  __attribute__((ext_vector_type(4)));

union U16B { uint4 u; bf16x8 b; };
static __device__ __forceinline__ bf16x8 u2b(uint4 u) { U16B x; x.u = u; return x.b; }

static __device__ __forceinline__ unsigned short f2bf(float f) {
  uint32_t u = __float_as_uint(f);
  u += 0x7fffu + ((u >> 16) & 1u);
  return (unsigned short)(u >> 16);
}

// ================= GEMM: out[m][n] = sum_k X[m][k]*W[n][k] + bias[n] ================
// MODE 0: plain fp32 out
// MODE 1: residual: out = gamma*(acc+bias) + xres
// MODE 2: Q: fp32 out (stride ostride) + aux = packed hi/lo bf16 [m][320] (cols>=150 zero)
// MODE 3: K: aux packed hi/lo bf16 only
// MODE 4: V: aux = V^T bf16 [b][col][4096]
template<int MODE>
__global__ __launch_bounds__(256)
void gemm_nt(const float* __restrict__ X, const float* __restrict__ W,
             const float* __restrict__ bias, float* __restrict__ out,
             int N, int ostride,
             const float* __restrict__ xres, const float* __restrict__ gammap,
             unsigned short* __restrict__ aux)
{
  __shared__ __align__(16) float as[16][132];
  __shared__ __align__(16) float bs[16][132];
  const int m0 = blockIdx.y * 128;
  const int n0 = blockIdx.x * 128;
  const int tid = threadIdx.x;
  const int tx = tid & 15, ty = tid >> 4;

  float acc[8][8];
#pragma unroll
  for (int i = 0; i < 8; ++i)
#pragma unroll
    for (int j = 0; j < 8; ++j) acc[i][j] = 0.f;

  for (int kt = 0; kt < 512; kt += 16) {
#pragma unroll
    for (int h = 0; h < 2; ++h) {
      const int f4 = tid + h * 256;      // 0..511
      const int row = f4 >> 2;           // 0..127
      const int kc = (f4 & 3) * 4;       // 0,4,8,12
      const float4 v = *(const float4*)&X[(size_t)(m0 + row) * 512 + kt + kc];
      as[kc + 0][row] = v.x; as[kc + 1][row] = v.y;
      as[kc + 2][row] = v.z; as[kc + 3][row] = v.w;
      const int wrow = n0 + row;
      float4 wv = make_float4(0.f, 0.f, 0.f, 0.f);
      if (wrow < N) wv = *(const float4*)&W[(size_t)wrow * 512 + kt + kc];
      bs[kc + 0][row] = wv.x; bs[kc + 1][row] = wv.y;
      bs[kc + 2][row] = wv.z; bs[kc + 3][row] = wv.w;
    }
    __syncthreads();
#pragma unroll 4
    for (int k = 0; k < 16; ++k) {
      float a[8], b[8];
      *(float4*)&a[0] = *(const float4*)&as[k][ty * 8];
      *(float4*)&a[4] = *(const float4*)&as[k][ty * 8 + 4];
      *(float4*)&b[0] = *(const float4*)&bs[k][tx * 8];
      *(float4*)&b[4] = *(const float4*)&bs[k][tx * 8 + 4];
#pragma unroll
      for (int i = 0; i < 8; ++i)
#pragma unroll
        for (int j = 0; j < 8; ++j)
          acc[i][j] = fmaf(a[i], b[j], acc[i][j]);
    }
    __syncthreads();
  }

  float bvv[8];
#pragma unroll
  for (int j = 0; j < 8; ++j) {
    const int n = n0 + tx * 8 + j;
    bvv[j] = (n < N) ? bias[n] : 0.f;
  }
  const int nb = n0 + tx * 8;

  if (MODE == 4) {
    const int b = m0 >> 12;
    const int key0 = (m0 & 4095) + ty * 8;
#pragma unroll
    for (int j = 0; j < 8; ++j) {
      const int col = nb + j;
      unsigned short o8[8];
#pragma unroll
      for (int i = 0; i < 8; ++i) o8[i] = f2bf(acc[i][j] + bvv[j]);
      *(uint4*)&aux[((size_t)(b * 512 + col)) * 4096 + key0] = *(uint4*)&o8[0];
    }
    return;
  }

  const float g = (MODE == 1) ? gammap[0] : 0.f;
#pragma unroll
  for (int i = 0; i < 8; ++i) {
    const int m = m0 + ty * 8 + i;
    float vals[8];
#pragma unroll
    for (int j = 0; j < 8; ++j) vals[j] = acc[i][j] + bvv[j];

    if (MODE == 1) {
      const float4 xr0 = *(const float4*)&xres[(size_t)m * CDIM + nb];
      const float4 xr1 = *(const float4*)&xres[(size_t)m * CDIM + nb + 4];
      vals[0] = fmaf(g, vals[0], xr0.x); vals[1] = fmaf(g, vals[1], xr0.y);
      vals[2] = fmaf(g, vals[2], xr0.z); vals[3] = fmaf(g, vals[3], xr0.w);
      vals[4] = fmaf(g, vals[4], xr1.x); vals[5] = fmaf(g, vals[5], xr1.y);
      vals[6] = fmaf(g, vals[6], xr1.z); vals[7] = fmaf(g, vals[7], xr1.w);
      *(float4*)&out[(size_t)m * ostride + nb] = make_float4(vals[0], vals[1], vals[2], vals[3]);
      *(float4*)&out[(size_t)m * ostride + nb + 4] = make_float4(vals[4], vals[5], vals[6], vals[7]);
    } else if (MODE == 0) {
#pragma unroll
      for (int j = 0; j < 8; ++j)
        if (nb + j < N) out[(size_t)m * ostride + nb + j] = vals[j];
    } else {  // MODE 2 / 3
      unsigned short hi8[8], lo8[8];
#pragma unroll
      for (int j = 0; j < 8; ++j) {
        const int n = nb + j;
        float v = (n < KRANK) ? vals[j] : 0.f;
        if (MODE == 2 && n < KRANK) out[(size_t)m * ostride + n] = v;
        const unsigned short h = f2bf(v);
        hi8[j] = h;
        const float hf = __uint_as_float(((uint32_t)h) << 16);
        lo8[j] = f2bf(v - hf);
      }
      if (nb < KPAD) {
        *(uint4*)&aux[(size_t)m * 320 + nb]       = *(uint4*)&hi8[0];
        *(uint4*)&aux[(size_t)m * 320 + 160 + nb] = *(uint4*)&lo8[0];
      }
    }
  }
}

// ================= MFMA flash attention (v3 fixed) =================
// 1024 blocks: batch = bid & 7 (XCD-affine), rem = bid>>3: qt = rem>>1 (64-row Q tile),
// ch = rem&1 (256-col half of V). 4 waves; wave w owns q-rows [w*16, w*16+16) for BOTH
// S and PV (wave-local softmax + wave-private P roundtrip -> 2 barriers/iter).
__global__ __launch_bounds__(256, 3)
void attn_mfma(const unsigned short* __restrict__ Qc,   // [32768][320] hi|lo
               const unsigned short* __restrict__ Kc,   // [32768][320] hi|lo
               const unsigned short* __restrict__ VT,   // [8][512][4096] bf16
               float* __restrict__ O)                   // [32768][512] fp32
{
  // klds 32x328, vtl 256x40, plds 4x(16x40)  => 46592 B (x3 blocks = 139.8 KB/CU)
  __shared__ __align__(16) unsigned short smem[23296];
  unsigned short* klds = smem;              // 32 keys x 328 (320 data + 8 pad)
  unsigned short* vtl  = smem + 10496;      // 256 cols x 40 (32 keys + 8 pad)
  unsigned short* plds = smem + 20736;      // per-wave 16 rows x 40

  const int bid = blockIdx.x;
  const int b   = bid & 7;                  // XCD-affine batch
  const int rem = bid >> 3;
  const int qt  = rem >> 1;
  const int ch  = rem & 1;
  const int r0  = (b << 12) + qt * 64;
  const int cb0 = ch * 256;

  const int tid  = threadIdx.x;
  const int w    = tid >> 6;
  const int lane = tid & 63;
  const int quad = lane >> 4;
  const int cq   = lane & 15;

  // ---- persistent Q fragments (A-operand layout) ----
  bf16x8 qhi[5], qlo[5];
  {
    const size_t qrow = (size_t)(r0 + w * 16 + cq) * 320;
#pragma unroll
    for (int c = 0; c < 5; ++c) {
      qhi[c] = u2b(*(const uint4*)(Qc + qrow + c * 32 + quad * 8));
      qlo[c] = u2b(*(const uint4*)(Qc + qrow + 160 + c * 32 + quad * 8));
    }
  }

  f32x4 acc4[16];
#pragma unroll
  for (int i = 0; i < 16; ++i) acc4[i] = (f32x4){0.f, 0.f, 0.f, 0.f};
  float mreg[4], lreg[4];
#pragma unroll
  for (int r = 0; r < 4; ++r) { mreg[r] = -3.0e38f; lreg[r] = 0.f; }

  const int vqd = (tid & 3) * 8;        // key sub-offset (uint4 granules of 8 ushorts)
  const int vc  = tid >> 2;             // 0..63 column group

  for (int kt = 0; kt < 128; ++kt) {
    __syncthreads();  // A: previous tile's LDS readers done

    // ---- stage K tile: 32 rows x 320 ushorts = 1280 uint4, 5 per thread ----
    {
      const unsigned short* kb_p = Kc + (size_t)(b * 4096 + kt * 32) * 320;
#pragma unroll
      for (int j = 0; j < 5; ++j) {
        const int idx = tid + 256 * j;             // 0..1279 (uint4 units)
        const uint4 t = *(const uint4*)(kb_p + (size_t)idx * 8);
        const int row = idx / 40;
        const int col8 = (idx - row * 40) * 8;
        *(uint4*)&klds[row * 328 + col8] = t;
      }
      // ---- stage V tile: 256 cols x 32 keys = 1024 uint4, 4 per thread ----
#pragma unroll
      for (int j = 0; j < 4; ++j) {
        const int col = vc + j * 64;               // 0..255
        const uint4 v = *(const uint4*)(VT + (size_t)(b * 512 + cb0 + col) * 4096
                                           + kt * 32 + vqd);
        *(uint4*)&vtl[col * 40 + vqd] = v;
      }
    }

    __syncthreads();  // B: staging visible

    // ---- S phase: wave w -> rows [w*16, w*16+16) x 32 keys ----
    f32x4 S0 = (f32x4){0.f, 0.f, 0.f, 0.f};
    f32x4 S1 = (f32x4){0.f, 0.f, 0.f, 0.f};
#pragma unroll
    for (int c = 0; c < 5; ++c) {
      const int ko = c * 32 + quad * 8;
      const bf16x8 kh0 = u2b(*(const uint4*)&klds[cq * 328 + ko]);
      const bf16x8 kl0 = u2b(*(const uint4*)&klds[cq * 328 + 160 + ko]);
      const bf16x8 kh1 = u2b(*(const uint4*)&klds[(16 + cq) * 328 + ko]);
      const bf16x8 kl1 = u2b(*(const uint4*)&klds[(16 + cq) * 328 + 160 + ko]);
      S0 = __builtin_amdgcn_mfma_f32_16x16x32_bf16(qhi[c], kh0, S0, 0, 0, 0);
      S1 = __builtin_amdgcn_mfma_f32_16x16x32_bf16(qhi[c], kh1, S1, 0, 0, 0);
      S0 = __builtin_amdgcn_mfma_f32_16x16x32_bf16(qhi[c], kl0, S0, 0, 0, 0);
      S1 = __builtin_amdgcn_mfma_f32_16x16x32_bf16(qhi[c], kl1, S1, 0, 0, 0);
      S0 = __builtin_amdgcn_mfma_f32_16x16x32_bf16(qlo[c], kh0, S0, 0, 0, 0);
      S1 = __builtin_amdgcn_mfma_f32_16x16x32_bf16(qlo[c], kh1, S1, 0, 0, 0);
    }

    // ---- wave-local online softmax (row = quad*4+r, keys cq / 16+cq) ----
    unsigned short* pw = plds + w * 640;
    float alph[4];
    bool upd = false;
#pragma unroll
    for (int r = 0; r < 4; ++r) {
      const float s0 = S0[r], s1 = S1[r];
      float t = fmaxf(s0, s1);
      t = fmaxf(t, __shfl_xor(t, 1));
      t = fmaxf(t, __shfl_xor(t, 2));
      t = fmaxf(t, __shfl_xor(t, 4));
      t = fmaxf(t, __shfl_xor(t, 8));
      const float mo = mreg[r];
      const float mn = fmaxf(mo, t);
      upd = upd || (mn > mo);
      const float al = __expf(mo - mn);
      const float p0 = __expf(s0 - mn);
      const float p1 = __expf(s1 - mn);
      float ts = p0 + p1;
      ts += __shfl_xor(ts, 1);
      ts += __shfl_xor(ts, 2);
      ts += __shfl_xor(ts, 4);
      ts += __shfl_xor(ts, 8);
      lreg[r] = lreg[r] * al + ts;
      mreg[r] = mn;
      alph[r] = al;
      const int prow = (quad * 4 + r) * 40;
      pw[prow + cq]      = f2bf(p0);
      pw[prow + 16 + cq] = f2bf(p1);
    }

    if (__any(upd)) {
#pragma unroll
      for (int i = 0; i < 16; ++i) {
        acc4[i][0] *= alph[0]; acc4[i][1] *= alph[1];
        acc4[i][2] *= alph[2]; acc4[i][3] *= alph[3];
      }
    }

    // ---- PV phase (wave-local): rows [w*16..) x cols [cb0, cb0+256) ----
    const bf16x8 pa = u2b(*(const uint4*)&pw[cq * 40 + quad * 8]);
#pragma unroll
    for (int i = 0; i < 16; ++i) {
      const bf16x8 vb = u2b(*(const uint4*)&vtl[(i * 16 + cq) * 40 + quad * 8]);
      acc4[i] = __builtin_amdgcn_mfma_f32_16x16x32_bf16(pa, vb, acc4[i], 0, 0, 0);
    }
  }

  // ---- epilogue: O = acc/l, staged through LDS for contiguous 512B stores ----
  float inv[4];
#pragma unroll
  for (int r = 0; r < 4; ++r) inv[r] = 1.f / lreg[r];

  __syncthreads();  // all waves done with klds/vtl before overlay
  float* ep = (float*)smem + w * 2112;     // 16 rows x 132 fp32 per wave
  const int r0w = r0 + w * 16;
#pragma unroll
  for (int half = 0; half < 2; ++half) {
    const int ib = half * 8;
#pragma unroll
    for (int i = 0; i < 8; ++i)
#pragma unroll
      for (int r = 0; r < 4; ++r)
        ep[(quad * 4 + r) * 132 + i * 16 + cq] = acc4[ib + i][r] * inv[r];
    // wave-private RAW; ds ops complete in order per wave
#pragma unroll
    for (int t = 0; t < 8; ++t) {
      const int flat = t * 64 + lane;      // 0..511
      const int row = flat >> 5;           // 0..15
      const int c4 = flat & 31;
      const float4 val = *(const float4*)&ep[row * 132 + c4 * 4];
      *(float4*)&O[(size_t)(r0w + row) * CDIM + cb0 + half * 128 + c4 * 4] = val;
    }
  }
}

extern "C" void kernel_launch(void* const* d_in, const int* in_sizes, int n_in,
                              void* d_out, int out_size, void* d_ws, size_t ws_size,
                              hipStream_t stream)
{
  const float* x     = (const float*)d_in[0];
  const float* Wq    = (const float*)d_in[1];
  const float* bq    = (const float*)d_in[2];
  const float* Wk    = (const float*)d_in[3];
  const float* bk    = (const float*)d_in[4];
  const float* Wv    = (const float*)d_in[5];
  const float* bv    = (const float*)d_in[6];
  const float* Wres  = (const float*)d_in[7];
  const float* bres  = (const float*)d_in[8];
  const float* gamma = (const float*)d_in[9];

  float* seg_map  = (float*)d_out;                         // 32768 x 150
  float* feat_map = seg_map + (size_t)M_ROWS * KRANK;      // 32768 x 512

  unsigned short* Qcomb = (unsigned short*)d_ws;                       // [32768][320]
  unsigned short* Kcomb = Qcomb + (size_t)M_ROWS * 320;                // [32768][320]
  unsigned short* VTb   = Kcomb + (size_t)M_ROWS * 320;                // [8][512][4096]
  float*          feats = (float*)(VTb + (size_t)M_ROWS * CDIM);       // [32768][512]

  dim3 blk(256);
  gemm_nt<2><<<dim3(2, 256), blk, 0, stream>>>(x, Wq, bq, seg_map, KRANK, KRANK, nullptr, nullptr, Qcomb);
  gemm_nt<3><<<dim3(2, 256), blk, 0, stream>>>(x, Wk, bk, nullptr,  KRANK, KRANK, nullptr, nullptr, Kcomb);
  gemm_nt<4><<<dim3(4, 256), blk, 0, stream>>>(x, Wv, bv, nullptr,  CDIM,  CDIM,  nullptr, nullptr, VTb);
  attn_mfma<<<dim3(1024), blk, 0, stream>>>(Qcomb, Kcomb, VTb, feats);
  gemm_nt<1><<<dim3(4, 256), blk, 0, stream>>>(feats, Wres, bres, feat_map, CDIM, CDIM, x, gamma, nullptr);
}

// Round 6
// 1352.885 us; speedup vs baseline: 4.8136x; 1.4002x over previous
//
#include <hip/hip_runtime.h>
#include <cstdint>
#include <cstddef>

#define M_ROWS 32768   // B*N
#define CDIM   512
#define KRANK  150
#define KPAD   160     // padded rank for MFMA (zeros beyond 150)

typedef __bf16 bf16x8 __attribute__((ext_vector_type(8)));
typedef float  f32x4  __attribute__((ext_vector_type(4)));

union U16B { uint4 u; bf16x8 b; };
static __device__ __forceinline__ bf16x8 u2b(uint4 u) { U16B x; x.u = u; return x.b; }

static __device__ __forceinline__ unsigned short f2bf(float f) {
  uint32_t u = __float_as_uint(f);
  u += 0x7fffu + ((u >> 16) & 1u);
  return (unsigned short)(u >> 16);
}

// ================= GEMM: out[m][n] = sum_k X[m][k]*W[n][k] + bias[n] ================
// MODE 0: plain fp32 out
// MODE 1: residual: out = gamma*(acc+bias) + xres
// MODE 2: Q: fp32 out (stride ostride) + aux = packed hi/lo bf16 [m][320] (cols>=150 zero)
// MODE 3: K: aux packed hi/lo bf16 only
// MODE 4: V: aux = V^T bf16 [b][col][4096]
template<int MODE>
__global__ __launch_bounds__(256)
void gemm_nt(const float* __restrict__ X, const float* __restrict__ W,
             const float* __restrict__ bias, float* __restrict__ out,
             int N, int ostride,
             const float* __restrict__ xres, const float* __restrict__ gammap,
             unsigned short* __restrict__ aux)
{
  __shared__ __align__(16) float as[16][132];
  __shared__ __align__(16) float bs[16][132];
  const int m0 = blockIdx.y * 128;
  const int n0 = blockIdx.x * 128;
  const int tid = threadIdx.x;
  const int tx = tid & 15, ty = tid >> 4;

  float acc[8][8];
#pragma unroll
  for (int i = 0; i < 8; ++i)
#pragma unroll
    for (int j = 0; j < 8; ++j) acc[i][j] = 0.f;

  for (int kt = 0; kt < 512; kt += 16) {
#pragma unroll
    for (int h = 0; h < 2; ++h) {
      const int f4 = tid + h * 256;      // 0..511
      const int row = f4 >> 2;           // 0..127
      const int kc = (f4 & 3) * 4;       // 0,4,8,12
      const float4 v = *(const float4*)&X[(size_t)(m0 + row) * 512 + kt + kc];
      as[kc + 0][row] = v.x; as[kc + 1][row] = v.y;
      as[kc + 2][row] = v.z; as[kc + 3][row] = v.w;
      const int wrow = n0 + row;
      float4 wv = make_float4(0.f, 0.f, 0.f, 0.f);
      if (wrow < N) wv = *(const float4*)&W[(size_t)wrow * 512 + kt + kc];
      bs[kc + 0][row] = wv.x; bs[kc + 1][row] = wv.y;
      bs[kc + 2][row] = wv.z; bs[kc + 3][row] = wv.w;
    }
    __syncthreads();
#pragma unroll 4
    for (int k = 0; k < 16; ++k) {
      float a[8], b[8];
      *(float4*)&a[0] = *(const float4*)&as[k][ty * 8];
      *(float4*)&a[4] = *(const float4*)&as[k][ty * 8 + 4];
      *(float4*)&b[0] = *(const float4*)&bs[k][tx * 8];
      *(float4*)&b[4] = *(const float4*)&bs[k][tx * 8 + 4];
#pragma unroll
      for (int i = 0; i < 8; ++i)
#pragma unroll
        for (int j = 0; j < 8; ++j)
          acc[i][j] = fmaf(a[i], b[j], acc[i][j]);
    }
    __syncthreads();
  }

  float bvv[8];
#pragma unroll
  for (int j = 0; j < 8; ++j) {
    const int n = n0 + tx * 8 + j;
    bvv[j] = (n < N) ? bias[n] : 0.f;
  }
  const int nb = n0 + tx * 8;

  if (MODE == 4) {
    const int b = m0 >> 12;
    const int key0 = (m0 & 4095) + ty * 8;
#pragma unroll
    for (int j = 0; j < 8; ++j) {
      const int col = nb + j;
      unsigned short o8[8];
#pragma unroll
      for (int i = 0; i < 8; ++i) o8[i] = f2bf(acc[i][j] + bvv[j]);
      *(uint4*)&aux[((size_t)(b * 512 + col)) * 4096 + key0] = *(uint4*)&o8[0];
    }
    return;
  }

  const float g = (MODE == 1) ? gammap[0] : 0.f;
#pragma unroll
  for (int i = 0; i < 8; ++i) {
    const int m = m0 + ty * 8 + i;
    float vals[8];
#pragma unroll
    for (int j = 0; j < 8; ++j) vals[j] = acc[i][j] + bvv[j];

    if (MODE == 1) {
      const float4 xr0 = *(const float4*)&xres[(size_t)m * CDIM + nb];
      const float4 xr1 = *(const float4*)&xres[(size_t)m * CDIM + nb + 4];
      vals[0] = fmaf(g, vals[0], xr0.x); vals[1] = fmaf(g, vals[1], xr0.y);
      vals[2] = fmaf(g, vals[2], xr0.z); vals[3] = fmaf(g, vals[3], xr0.w);
      vals[4] = fmaf(g, vals[4], xr1.x); vals[5] = fmaf(g, vals[5], xr1.y);
      vals[6] = fmaf(g, vals[6], xr1.z); vals[7] = fmaf(g, vals[7], xr1.w);
      *(float4*)&out[(size_t)m * ostride + nb] = make_float4(vals[0], vals[1], vals[2], vals[3]);
      *(float4*)&out[(size_t)m * ostride + nb + 4] = make_float4(vals[4], vals[5], vals[6], vals[7]);
    } else if (MODE == 0) {
#pragma unroll
      for (int j = 0; j < 8; ++j)
        if (nb + j < N) out[(size_t)m * ostride + nb + j] = vals[j];
    } else {  // MODE 2 / 3
      unsigned short hi8[8], lo8[8];
#pragma unroll
      for (int j = 0; j < 8; ++j) {
        const int n = nb + j;
        float v = (n < KRANK) ? vals[j] : 0.f;
        if (MODE == 2 && n < KRANK) out[(size_t)m * ostride + n] = v;
        const unsigned short h = f2bf(v);
        hi8[j] = h;
        const float hf = __uint_as_float(((uint32_t)h) << 16);
        lo8[j] = f2bf(v - hf);
      }
      if (nb < KPAD) {
        *(uint4*)&aux[(size_t)m * 320 + nb]       = *(uint4*)&hi8[0];
        *(uint4*)&aux[(size_t)m * 320 + 160 + nb] = *(uint4*)&lo8[0];
      }
    }
  }
}

// ================= MFMA flash attention (v5) =================
// 512 blocks: b = bid&7 (XCD-affine), ch = (bid>>3)&1 (256-col half), qt = bid>>4.
// 512 threads = 8 waves; wave w owns q-rows [w*16, w*16+16) x this col-half for S AND PV
// (everything wave-private, 2 barriers/iter). Register prefetch issued post-barrier-B
// so global loads are in flight for the whole compute phase.
__global__ __launch_bounds__(512, 2)
void attn_mfma(const unsigned short* __restrict__ Qc,   // [32768][320] hi|lo
               const unsigned short* __restrict__ Kc,   // [32768][320] hi|lo
               const unsigned short* __restrict__ VT,   // [8][512][4096] bf16
               float* __restrict__ O)                   // [32768][512] fp32
{
  // klds 32x328 (10496) + vtl 256x40 (10240) + plds 8x(16x40) (5120) = 25856 ush = 51712 B
  __shared__ __align__(16) unsigned short smem[25856];
  unsigned short* klds = smem;              // 32 keys x 328 (320 data + 8 pad)
  unsigned short* vtl  = smem + 10496;      // 256 cols x 40 (32 keys + 8 pad)
  unsigned short* plds = smem + 20736;      // per-wave 16 rows x 40

  const int bid = blockIdx.x;
  const int b   = bid & 7;                  // XCD-affine batch
  const int ch  = (bid >> 3) & 1;
  const int qt  = bid >> 4;                 // 0..31
  const int r0  = (b << 12) + qt * 128;
  const int cb0 = ch * 256;

  const int tid  = threadIdx.x;             // 0..511
  const int w    = tid >> 6;                // 0..7
  const int lane = tid & 63;
  const int quad = lane >> 4;
  const int cq   = lane & 15;

  // ---- persistent Q fragments (A-operand layout), rows r0 + w*16 + cq ----
  bf16x8 qhi[5], qlo[5];
  {
    const size_t qrow = (size_t)(r0 + w * 16 + cq) * 320;
#pragma unroll
    for (int c = 0; c < 5; ++c) {
      qhi[c] = u2b(*(const uint4*)(Qc + qrow + c * 32 + quad * 8));
      qlo[c] = u2b(*(const uint4*)(Qc + qrow + 160 + c * 32 + quad * 8));
    }
  }

  f32x4 acc4[16];
#pragma unroll
  for (int i = 0; i < 16; ++i) acc4[i] = (f32x4){0.f, 0.f, 0.f, 0.f};
  float mreg[4], lreg[4];
#pragma unroll
  for (int r = 0; r < 4; ++r) { mreg[r] = -3.0e38f; lreg[r] = 0.f; }

  const int vqd = (tid & 3) * 8;        // V key sub-offset (8 ushorts)
  const int vc  = tid >> 2;             // 0..127 column group

  // K staging geometry (1280 uint4 cells): p = tid, tid+512, (tid<256: tid+1024)
  const int krow0 = tid / 40,          kc0 = (tid - krow0 * 40) * 8;
  const int krow1 = (tid + 512) / 40,  kc1 = ((tid + 512) - krow1 * 40) * 8;
  const int krow2 = (tid + 1024) / 40, kc2 = ((tid + 1024) - krow2 * 40) * 8;

  uint4 pk0, pk1, pk2, pv0, pv1;
  // ---- initial prefetch (tile 0) ----
  {
    const unsigned short* kb_p = Kc + (size_t)(b * 4096) * 320;
    pk0 = *(const uint4*)(kb_p + (size_t)tid * 8);
    pk1 = *(const uint4*)(kb_p + (size_t)(tid + 512) * 8);
    if (tid < 256) pk2 = *(const uint4*)(kb_p + (size_t)(tid + 1024) * 8);
    const unsigned short* vb_p = VT + ((size_t)(b * 512 + cb0 + vc)) * 4096 + vqd;
    pv0 = *(const uint4*)(vb_p);
    pv1 = *(const uint4*)(vb_p + (size_t)128 * 4096);
  }

  for (int kt = 0; kt < 128; ++kt) {
    __syncthreads();  // A: previous tile's LDS readers done; drains prefetch loads

    // ---- stage prefetched K / V tiles into LDS ----
    *(uint4*)&klds[krow0 * 328 + kc0] = pk0;
    *(uint4*)&klds[krow1 * 328 + kc1] = pk1;
    if (tid < 256) *(uint4*)&klds[krow2 * 328 + kc2] = pk2;
    *(uint4*)&vtl[vc * 40 + vqd] = pv0;
    *(uint4*)&vtl[(vc + 128) * 40 + vqd] = pv1;

    __syncthreads();  // B: staging visible

    // ---- issue prefetch for next tile (in flight during S+softmax+PV) ----
    {
      const int ktn = (kt < 127) ? kt + 1 : 127;
      const unsigned short* kb_p = Kc + (size_t)(b * 4096 + ktn * 32) * 320;
      pk0 = *(const uint4*)(kb_p + (size_t)tid * 8);
      pk1 = *(const uint4*)(kb_p + (size_t)(tid + 512) * 8);
      if (tid < 256) pk2 = *(const uint4*)(kb_p + (size_t)(tid + 1024) * 8);
      const unsigned short* vb_p = VT + ((size_t)(b * 512 + cb0 + vc)) * 4096 + ktn * 32 + vqd;
      pv0 = *(const uint4*)(vb_p);
      pv1 = *(const uint4*)(vb_p + (size_t)128 * 4096);
    }

    // ---- S phase: wave w -> rows [w*16, w*16+16) x 32 keys ----
    f32x4 S0 = (f32x4){0.f, 0.f, 0.f, 0.f};
    f32x4 S1 = (f32x4){0.f, 0.f, 0.f, 0.f};
#pragma unroll
    for (int c = 0; c < 5; ++c) {
      const int ko = c * 32 + quad * 8;
      const bf16x8 kh0 = u2b(*(const uint4*)&klds[cq * 328 + ko]);
      const bf16x8 kl0 = u2b(*(const uint4*)&klds[cq * 328 + 160 + ko]);
      const bf16x8 kh1 = u2b(*(const uint4*)&klds[(16 + cq) * 328 + ko]);
      const bf16x8 kl1 = u2b(*(const uint4*)&klds[(16 + cq) * 328 + 160 + ko]);
      S0 = __builtin_amdgcn_mfma_f32_16x16x32_bf16(qhi[c], kh0, S0, 0, 0, 0);
      S1 = __builtin_amdgcn_mfma_f32_16x16x32_bf16(qhi[c], kh1, S1, 0, 0, 0);
      S0 = __builtin_amdgcn_mfma_f32_16x16x32_bf16(qhi[c], kl0, S0, 0, 0, 0);
      S1 = __builtin_amdgcn_mfma_f32_16x16x32_bf16(qhi[c], kl1, S1, 0, 0, 0);
      S0 = __builtin_amdgcn_mfma_f32_16x16x32_bf16(qlo[c], kh0, S0, 0, 0, 0);
      S1 = __builtin_amdgcn_mfma_f32_16x16x32_bf16(qlo[c], kh1, S1, 0, 0, 0);
    }

    // ---- wave-local online softmax (row = quad*4+r, keys cq / 16+cq) ----
    unsigned short* pw = plds + w * 640;
    float alph[4];
    bool upd = false;
#pragma unroll
    for (int r = 0; r < 4; ++r) {
      const float s0 = S0[r], s1 = S1[r];
      float t = fmaxf(s0, s1);
      t = fmaxf(t, __shfl_xor(t, 1));
      t = fmaxf(t, __shfl_xor(t, 2));
      t = fmaxf(t, __shfl_xor(t, 4));
      t = fmaxf(t, __shfl_xor(t, 8));
      const float mo = mreg[r];
      const float mn = fmaxf(mo, t);
      upd = upd || (mn > mo);
      const float al = __expf(mo - mn);
      const float p0 = __expf(s0 - mn);
      const float p1 = __expf(s1 - mn);
      float ts = p0 + p1;
      ts += __shfl_xor(ts, 1);
      ts += __shfl_xor(ts, 2);
      ts += __shfl_xor(ts, 4);
      ts += __shfl_xor(ts, 8);
      lreg[r] = lreg[r] * al + ts;
      mreg[r] = mn;
      alph[r] = al;
      const int prow = (quad * 4 + r) * 40;
      pw[prow + cq]      = f2bf(p0);
      pw[prow + 16 + cq] = f2bf(p1);
    }

    if (__any(upd)) {
#pragma unroll
      for (int i = 0; i < 16; ++i) {
        acc4[i][0] *= alph[0]; acc4[i][1] *= alph[1];
        acc4[i][2] *= alph[2]; acc4[i][3] *= alph[3];
      }
    }

    // ---- PV phase (wave-local): rows [w*16..) x cols [cb0, cb0+256) ----
    const bf16x8 pa = u2b(*(const uint4*)&pw[cq * 40 + quad * 8]);
#pragma unroll
    for (int i = 0; i < 16; ++i) {
      const bf16x8 vb = u2b(*(const uint4*)&vtl[(i * 16 + cq) * 40 + quad * 8]);
      acc4[i] = __builtin_amdgcn_mfma_f32_16x16x32_bf16(pa, vb, acc4[i], 0, 0, 0);
    }
  }

  // ---- epilogue: O = acc/l, staged through LDS (64-col quarters) ----
  float inv[4];
#pragma unroll
  for (int r = 0; r < 4; ++r) inv[r] = 1.f / lreg[r];

  __syncthreads();  // all waves done with klds/vtl before overlay
  float* ep = (float*)smem + w * 1088;     // 16 rows x 68 fp32 per wave (4352 B)
  const int r0w = r0 + w * 16;
#pragma unroll
  for (int qtr = 0; qtr < 4; ++qtr) {
#pragma unroll
    for (int ii = 0; ii < 4; ++ii)
#pragma unroll
      for (int r = 0; r < 4; ++r)
        ep[(quad * 4 + r) * 68 + ii * 16 + cq] = acc4[qtr * 4 + ii][r] * inv[r];
    // wave-private RAW; ds ops complete in order per wave
#pragma unroll
    for (int t = 0; t < 4; ++t) {
      const int flat4 = t * 64 + lane;     // 0..255 float4 units (16 rows x 16)
      const int row = flat4 >> 4;          // 0..15
      const int c4 = flat4 & 15;
      const float4 val = *(const float4*)&ep[row * 68 + c4 * 4];
      *(float4*)&O[(size_t)(r0w + row) * CDIM + cb0 + qtr * 64 + c4 * 4] = val;
    }
  }
}

extern "C" void kernel_launch(void* const* d_in, const int* in_sizes, int n_in,
                              void* d_out, int out_size, void* d_ws, size_t ws_size,
                              hipStream_t stream)
{
  const float* x     = (const float*)d_in[0];
  const float* Wq    = (const float*)d_in[1];
  const float* bq    = (const float*)d_in[2];
  const float* Wk    = (const float*)d_in[3];
  const float* bk    = (const float*)d_in[4];
  const float* Wv    = (const float*)d_in[5];
  const float* bv    = (const float*)d_in[6];
  const float* Wres  = (const float*)d_in[7];
  const float* bres  = (const float*)d_in[8];
  const float* gamma = (const float*)d_in[9];

  float* seg_map  = (float*)d_out;                         // 32768 x 150
  float* feat_map = seg_map + (size_t)M_ROWS * KRANK;      // 32768 x 512

  unsigned short* Qcomb = (unsigned short*)d_ws;                       // [32768][320]
  unsigned short* Kcomb = Qcomb + (size_t)M_ROWS * 320;                // [32768][320]
  unsigned short* VTb   = Kcomb + (size_t)M_ROWS * 320;                // [8][512][4096]
  float*          feats = (float*)(VTb + (size_t)M_ROWS * CDIM);       // [32768][512]

  dim3 blk(256);
  gemm_nt<2><<<dim3(2, 256), blk, 0, stream>>>(x, Wq, bq, seg_map, KRANK, KRANK, nullptr, nullptr, Qcomb);
  gemm_nt<3><<<dim3(2, 256), blk, 0, stream>>>(x, Wk, bk, nullptr,  KRANK, KRANK, nullptr, nullptr, Kcomb);
  gemm_nt<4><<<dim3(4, 256), blk, 0, stream>>>(x, Wv, bv, nullptr,  CDIM,  CDIM,  nullptr, nullptr, VTb);
  attn_mfma<<<dim3(512), dim3(512), 0, stream>>>(Qcomb, Kcomb, VTb, feats);
  gemm_nt<1><<<dim3(4, 256), blk, 0, stream>>>(feats, Wres, bres, feat_map, CDIM, CDIM, x, gamma, nullptr);
}